// Round 15
// baseline (179.308 us; speedup 1.0000x reference)
//
#include <hip/hip_runtime.h>

#define TSEQ 2048
#define CDIM 1024
#define NH 16
#define DH 64
#define NB 4

typedef __bf16 bf16x8 __attribute__((ext_vector_type(8)));
typedef float f32x4 __attribute__((ext_vector_type(4)));

// 1/sqrt(C) * log2(e): folded into Q so softmax runs in exp2 domain
#define QSCALE 0.04508422f

static __device__ __forceinline__ ushort f2bf(float f) {
  unsigned u = __float_as_uint(f);
  unsigned r = u + 0x7fffu + ((u >> 16) & 1u);
  return (ushort)(r >> 16);
}

static __device__ __forceinline__ uint cvtpk(float lo, float hi) {
  uint r;
  asm("v_cvt_pk_bf16_f32 %0, %1, %2" : "=v"(r) : "v"(lo), "v"(hi));
  return r;
}

// global(16B, per-lane addr) -> LDS (wave-uniform base, HW adds lane*16)
static __device__ __forceinline__ void gload_lds16(const void* g, void* ldsbase) {
  __builtin_amdgcn_global_load_lds((const __attribute__((address_space(1))) void*)g,
                                   (__attribute__((address_space(3))) void*)ldsbase,
                                   16, 0, 0);
}

// ONE prep launch. z<3: W{q,k,v}[16][1024][64] -> wall [z][head][64][1024];
// z==3: Wp -> wpT; z in [4,12): x f32 -> xb bf16.
__global__ void prep_kernel(const float* __restrict__ x,
                            const float* __restrict__ Wq, const float* __restrict__ Wk,
                            const float* __restrict__ Wv, const float* __restrict__ Wp,
                            ushort* __restrict__ xb, ushort* __restrict__ wall,
                            ushort* __restrict__ wpT) {
  __shared__ float tile[32][33];
  const int z = blockIdx.z;
  const int tx = threadIdx.x, ty = threadIdx.y;
  if (z >= 4) {
    int blk = (z - 4) * 1024 + blockIdx.y * 32 + blockIdx.x;
    int i = blk * 256 + ty * 32 + tx;
    float4 f = ((const float4*)x)[i];
    ushort4 o;
    o.x = f2bf(f.x); o.y = f2bf(f.y); o.z = f2bf(f.z); o.w = f2bf(f.w);
    ((ushort4*)xb)[i] = o;
    return;
  }
  const float* s; ushort* d; int Cc, c0, r0;
  if (z < 3) {
    const int head = blockIdx.x >> 1;
    s = (z == 0 ? Wq : z == 1 ? Wk : Wv) + (size_t)head * CDIM * DH;
    d = wall + ((size_t)z << 20) + (size_t)head * CDIM * DH;
    Cc = DH; c0 = (blockIdx.x & 1) * 32; r0 = blockIdx.y * 32;
  } else {
    s = Wp; d = wpT; Cc = CDIM; c0 = blockIdx.x * 32; r0 = blockIdx.y * 32;
  }
  for (int i = ty; i < 32; i += 8)
    tile[i][tx] = s[(size_t)(r0 + i) * Cc + c0 + tx];
  __syncthreads();
  for (int i = ty; i < 32; i += 8)
    d[(size_t)(c0 + i) * CDIM + r0 + tx] = f2bf(tile[tx][i]);
}

// 128x128-tile GEMM, DEPTH-2 prefetch via BUILTINS ONLY (no asm clobbers):
// 3 rotating 16KB buffers; per step: s_waitcnt(vmcnt 4) [0xF74: exp/lgkm
// unconstrained] -> s_barrier -> sched_barrier(0) -> prefetch(k+2) -> ds_read
// + MFMA on buf(k). Loads issued at step k are consumed at k+2, so two compute
// phases cover the L2/L3 latency; only the last steps drain to vmcnt(0).
// vmcnt accounting: each wave issues exactly 4 loads per tile.
// Rows are 64B; swizzle chunk ^= (row>>1)&3 is conflict-free on ds_read_b128.
// MODE 0: qkv (B^T = [3072][1024]; route by n). MODE 1: proj (f32 + bias).
// XCD chunk is nt-fastest: each XCD reads only 8 A-panels (2 MB, L2-resident).
template <int MODE>
__global__ __launch_bounds__(256) void gemm_kernel(
    const ushort* __restrict__ A, const ushort* __restrict__ Bt,
    const float* __restrict__ bp, float* __restrict__ fout,
    ushort* __restrict__ qb, ushort* __restrict__ kb, ushort* __restrict__ vTb) {
  __shared__ ushort lds[24576]; // 3 buf x (A 8KB + B 8KB) = 48KB
  const int tid = threadIdx.x, w = tid >> 6, l = tid & 63;
  const int nwg = gridDim.x;
  const int bid = blockIdx.x;
  const int wgid = (bid & 7) * (nwg >> 3) + (bid >> 3);
  const int NT = (MODE == 0) ? 24 : 8;
  const int nt = wgid % NT, mt = wgid / NT;
  const int wr = w >> 1, wc = w & 1;
  const int srw = l >> 2;
  const int sck = l & 3;
  const int scol = (sck ^ ((srw >> 1) & 3)) * 8;
  const int g = l >> 4;
  char* ldsb = (char*)lds;

  f32x4 acc[4][4] = {};

  const ushort* Arow = A + ((size_t)mt * 128) * CDIM;
  const ushort* Brow = Bt + ((size_t)nt * 128) * CDIM;

  // prologue: tile 0 -> buf0, tile 1 -> buf1 (4 loads/wave each)
#pragma unroll
  for (int i = 0; i < 4; ++i) {
    int ch = w * 4 + i;
    const ushort* src = (ch < 8) ? Arow + (size_t)(ch * 16 + srw) * CDIM + scol
                                 : Brow + (size_t)((ch - 8) * 16 + srw) * CDIM + scol;
    gload_lds16(src, ldsb + ch * 1024);
  }
#pragma unroll
  for (int i = 0; i < 4; ++i) {
    int ch = w * 4 + i;
    const ushort* src = (ch < 8) ? Arow + (size_t)(ch * 16 + srw) * CDIM + 32 + scol
                                 : Brow + (size_t)((ch - 8) * 16 + srw) * CDIM + 32 + scol;
    gload_lds16(src, ldsb + 16384 + ch * 1024);
  }

  int oc = 0, o1 = 16384, o2 = 32768; // rotating byte offsets: tiles k, k+1, k+2
#pragma unroll 1
  for (int k0 = 0; k0 < CDIM; k0 += 32) {
    if (k0 + 32 < CDIM) __builtin_amdgcn_s_waitcnt(0xF74); // vmcnt(4): tile k done
    else                __builtin_amdgcn_s_waitcnt(0xF70); // vmcnt(0): final drain
    __builtin_amdgcn_s_barrier();
    __builtin_amdgcn_sched_barrier(0);
    if (k0 + 64 < CDIM) { // prefetch tile k+2 into freed slot (readers passed barrier)
      char* nb = ldsb + o2;
#pragma unroll
      for (int i = 0; i < 4; ++i) {
        int ch = w * 4 + i;
        const ushort* src = (ch < 8)
            ? Arow + (size_t)(ch * 16 + srw) * CDIM + k0 + 64 + scol
            : Brow + (size_t)((ch - 8) * 16 + srw) * CDIM + k0 + 64 + scol;
        gload_lds16(src, nb + ch * 1024);
      }
    }
    char* base = ldsb + oc;
    bf16x8 af[4];
#pragma unroll
    for (int fm = 0; fm < 4; ++fm) {
      int row = wr * 64 + fm * 16 + (l & 15);
      af[fm] = *(const bf16x8*)(base + row * 64 + ((g ^ ((row >> 1) & 3)) << 4));
    }
#pragma unroll
    for (int fn = 0; fn < 4; ++fn) {
      int n = wc * 64 + fn * 16 + (l & 15);
      bf16x8 bfr = *(const bf16x8*)(base + 8192 + n * 64 + ((g ^ ((n >> 1) & 3)) << 4));
#pragma unroll
      for (int fm = 0; fm < 4; ++fm)
        acc[fm][fn] = __builtin_amdgcn_mfma_f32_16x16x32_bf16(af[fm], bfr, acc[fm][fn], 0, 0, 0);
    }
    int t = oc; oc = o1; o1 = o2; o2 = t; // rotate buffers
  }

#pragma unroll
  for (int fm = 0; fm < 4; ++fm) {
#pragma unroll
    for (int fn = 0; fn < 4; ++fn) {
      const int gr0 = mt * 128 + wr * 64 + fm * 16 + (l >> 4) * 4;
      const int gc = nt * 128 + wc * 64 + fn * 16 + (l & 15);
      if (MODE == 1) {
        float bias = bp[gc];
#pragma unroll
        for (int r = 0; r < 4; ++r)
          fout[(size_t)(gr0 + r) * CDIM + gc] = acc[fm][fn][r] + bias;
      } else {
        const int sel = gc >> 10, h = (gc >> 6) & 15, d = gc & 63;
        const int bh = (gr0 >> 11) * NH + h, tl = gr0 & 2047;
        if (sel == 2) {
          ushort4 pk;
          pk.x = f2bf(acc[fm][fn][0]); pk.y = f2bf(acc[fm][fn][1]);
          pk.z = f2bf(acc[fm][fn][2]); pk.w = f2bf(acc[fm][fn][3]);
          *(ushort4*)(vTb + ((size_t)bh * DH + d) * TSEQ + tl) = pk;
        } else if (sel == 0) {
#pragma unroll
          for (int r = 0; r < 4; ++r)
            qb[((size_t)bh * TSEQ + tl + r) * DH + d] = f2bf(acc[fm][fn][r] * QSCALE);
        } else {
#pragma unroll
          for (int r = 0; r < 4; ++r)
            kb[((size_t)bh * TSEQ + tl + r) * DH + d] = f2bf(acc[fm][fn][r]);
        }
      }
    }
  }
}

// Flash attention (R9/R13 structure, verified best): 1024 blocks x 256 threads
// (4 waves), 128-q tile, qt-descending + XCD-aware decode, KVBLK=64
// double-buffered, swapped QK^T, no cross-lane ops in the softmax common path.
__global__ __launch_bounds__(256, 3) void attn_kernel(
    const ushort* __restrict__ qb, const ushort* __restrict__ kb,
    const ushort* __restrict__ vTb, ushort* __restrict__ aob) {
  __shared__ ushort lds[16384];
  char* ldsb = (char*)lds;
  const int tid = threadIdx.x, w = tid >> 6, l = tid & 63;
  const int id = blockIdx.x;
  const int bh = (id & 7) * 8 + ((id >> 3) & 7);
  const int qt = 15 - (id >> 6);
  const int q0 = qt * 128;
  const int nt = 2 * (qt + 1);
  const int b = bh >> 4, h = bh & 15;
  const int g = l >> 4, q = l & 15;
  const int srow = l >> 3;
  const int scol = (((l & 7) ^ srow) << 3);
  const int adrA = ((l & 16) << 1 | q) << 2;
  const int adrB = adrA + 64;
  const bool hi32 = (l & 32) != 0;

  bf16x8 qf[2][2];
#pragma unroll
  for (int qs = 0; qs < 2; ++qs) {
    const ushort* qrow = qb + ((size_t)bh * TSEQ + q0 + w * 32 + qs * 16 + q) * DH;
    qf[qs][0] = *(const bf16x8*)(qrow + 8 * g);
    qf[qs][1] = *(const bf16x8*)(qrow + 32 + 8 * g);
  }

  float m[2] = {0.f, 0.f}, lsum[2] = {0.f, 0.f};
  f32x4 o[4][2] = {};

#pragma unroll
  for (int i = 0; i < 4; ++i) {
    int ch = w * 4 + i;
    if (ch < 8)
      gload_lds16(kb + ((size_t)bh * TSEQ + ch * 8 + srow) * DH + scol, ldsb + ch * 1024);
    else {
      int d = (ch - 8) * 8 + srow;
      gload_lds16(vTb + ((size_t)bh * DH + d) * TSEQ + scol, ldsb + 16384 + (ch - 8) * 1024);
    }
  }

#pragma unroll 1
  for (int j = 0; j < nt; ++j) {
    __syncthreads();
    const int cbuf = j & 1;
    if (j + 1 < nt) {
      const int kvn = (j + 1) * 64, nb = (j + 1) & 1;
#pragma unroll
      for (int i = 0; i < 4; ++i) {
        int ch = w * 4 + i;
        if (ch < 8)
          gload_lds16(kb + ((size_t)bh * TSEQ + kvn + ch * 8 + srow) * DH + scol,
                      ldsb + nb * 8192 + ch * 1024);
        else {
          int d = (ch - 8) * 8 + srow;
          gload_lds16(vTb + ((size_t)bh * DH + d) * TSEQ + kvn + scol,
                      ldsb + 16384 + nb * 8192 + (ch - 8) * 1024);
        }
      }
    }
    char* Kb = ldsb + cbuf * 8192;
    char* Vb = ldsb + 16384 + cbuf * 8192;

    f32x4 s[4][2] = {};
    __builtin_amdgcn_s_setprio(1);
#pragma unroll
    for (int ks = 0; ks < 2; ++ks)
#pragma unroll
      for (int fn = 0; fn < 4; ++fn) {
        int n = fn * 16 + q;
        int cbb = (ks * 64 + 16 * g) ^ ((n & 7) << 4);
        bf16x8 kf = *(const bf16x8*)(Kb + n * 128 + cbb);
        s[fn][0] = __builtin_amdgcn_mfma_f32_16x16x32_bf16(kf, qf[0][ks], s[fn][0], 0, 0, 0);
        s[fn][1] = __builtin_amdgcn_mfma_f32_16x16x32_bf16(kf, qf[1][ks], s[fn][1], 0, 0, 0);
      }
    __builtin_amdgcn_s_setprio(0);

    if (j >= nt - 2) {
#pragma unroll
      for (int qs = 0; qs < 2; ++qs) {
        int rowloc = q0 + w * 32 + qs * 16 + q - j * 64;
#pragma unroll
        for (int fn = 0; fn < 4; ++fn)
#pragma unroll
          for (int r = 0; r < 4; ++r)
            if (fn * 16 + 4 * g + r > rowloc) s[fn][qs][r] = -1e30f;
      }
    }

    float vmx[2];
#pragma unroll
    for (int qs = 0; qs < 2; ++qs) {
      float v = fmaxf(fmaxf(fmaxf(s[0][qs][0], s[0][qs][1]), fmaxf(s[0][qs][2], s[0][qs][3])),
                      fmaxf(fmaxf(s[1][qs][0], s[1][qs][1]), fmaxf(s[1][qs][2], s[1][qs][3])));
      v = fmaxf(v, fmaxf(fmaxf(fmaxf(s[2][qs][0], s[2][qs][1]), fmaxf(s[2][qs][2], s[2][qs][3])),
                         fmaxf(fmaxf(s[3][qs][0], s[3][qs][1]), fmaxf(s[3][qs][2], s[3][qs][3]))));
      vmx[qs] = v;
    }
    if (__any(fmaxf(vmx[0] - m[0], vmx[1] - m[1]) > 8.f)) {
      float fc[2];
#pragma unroll
      for (int qs = 0; qs < 2; ++qs) {
        float v = vmx[qs];
        v = fmaxf(v, __shfl_xor(v, 16));
        v = fmaxf(v, __shfl_xor(v, 32));
        float mn = fmaxf(m[qs], v);
        fc[qs] = __builtin_amdgcn_exp2f(m[qs] - mn);
        m[qs] = mn; lsum[qs] *= fc[qs];
      }
#pragma unroll
      for (int r = 0; r < 4; ++r) {
        float f0 = __shfl(fc[0], (l & 0x30) | (4 * g + r), 64);
        float f1 = __shfl(fc[1], (l & 0x30) | (4 * g + r), 64);
#pragma unroll
        for (int fn = 0; fn < 4; ++fn) { o[fn][0][r] *= f0; o[fn][1][r] *= f1; }
      }
    }

    uint D[2][4][2];
#pragma unroll
    for (int qs = 0; qs < 2; ++qs) {
      float rs = 0.f;
#pragma unroll
      for (int fn = 0; fn < 4; ++fn) {
        float p0 = __builtin_amdgcn_exp2f(s[fn][qs][0] - m[qs]);
        float p1 = __builtin_amdgcn_exp2f(s[fn][qs][1] - m[qs]);
        float p2 = __builtin_amdgcn_exp2f(s[fn][qs][2] - m[qs]);
        float p3 = __builtin_amdgcn_exp2f(s[fn][qs][3] - m[qs]);
        rs += (p0 + p1) + (p2 + p3);
        D[qs][fn][0] = cvtpk(p0, p1);
        D[qs][fn][1] = cvtpk(p2, p3);
      }
      lsum[qs] += rs;
    }

#pragma unroll
    for (int ksg = 0; ksg < 2; ++ksg) {
      union { uint u[4]; bf16x8 v; } P[2];
#pragma unroll
      for (int qs = 0; qs < 2; ++qs) {
        uint t0a = __builtin_amdgcn_ds_bpermute(adrA, (int)D[qs][2 * ksg][0]);
        uint t0b = __builtin_amdgcn_ds_bpermute(adrA, (int)D[qs][2 * ksg + 1][0]);
        uint t1a = __builtin_amdgcn_ds_bpermute(adrA, (int)D[qs][2 * ksg][1]);
        uint t1b = __builtin_amdgcn_ds_bpermute(adrA, (int)D[qs][2 * ksg + 1][1]);
        uint t2a = __builtin_amdgcn_ds_bpermute(adrB, (int)D[qs][2 * ksg][0]);
        uint t2b = __builtin_amdgcn_ds_bpermute(adrB, (int)D[qs][2 * ksg + 1][0]);
        uint t3a = __builtin_amdgcn_ds_bpermute(adrB, (int)D[qs][2 * ksg][1]);
        uint t3b = __builtin_amdgcn_ds_bpermute(adrB, (int)D[qs][2 * ksg + 1][1]);
        P[qs].u[0] = hi32 ? t0b : t0a;
        P[qs].u[1] = hi32 ? t1b : t1a;
        P[qs].u[2] = hi32 ? t2b : t2a;
        P[qs].u[3] = hi32 ? t3b : t3a;
      }
      __builtin_amdgcn_s_setprio(1);
#pragma unroll
      for (int fn = 0; fn < 4; ++fn) {
        int n = fn * 16 + q;
        int cbb = (ksg * 64 + 16 * g) ^ ((n & 7) << 4);
        bf16x8 vf = *(const bf16x8*)(Vb + n * 128 + cbb);
        o[fn][0] = __builtin_amdgcn_mfma_f32_16x16x32_bf16(P[0].v, vf, o[fn][0], 0, 0, 0);
        o[fn][1] = __builtin_amdgcn_mfma_f32_16x16x32_bf16(P[1].v, vf, o[fn][1], 0, 0, 0);
      }
      __builtin_amdgcn_s_setprio(0);
    }
  }

#pragma unroll
  for (int qs = 0; qs < 2; ++qs) {
    float tot = lsum[qs];
    tot += __shfl_xor(tot, 16);
    tot += __shfl_xor(tot, 32);
    float inv = 1.f / tot;
#pragma unroll
    for (int r = 0; r < 4; ++r) {
      float invq = __shfl(inv, (l & 0x30) | (4 * g + r), 64);
      int t = q0 + w * 32 + qs * 16 + 4 * g + r;
#pragma unroll
      for (int fn = 0; fn < 4; ++fn) {
        int d = fn * 16 + q;
        aob[((size_t)b * TSEQ + t) * (NH * DH) + h * DH + d] = f2bf(o[fn][qs][r] * invq);
      }
    }
  }
}

extern "C" void kernel_launch(void* const* d_in, const int* in_sizes, int n_in,
                              void* d_out, int out_size, void* d_ws, size_t ws_size,
                              hipStream_t stream) {
  (void)in_sizes; (void)n_in; (void)out_size; (void)ws_size;
  const float* x  = (const float*)d_in[0];
  const float* Wq = (const float*)d_in[1];
  const float* Wk = (const float*)d_in[2];
  const float* Wv = (const float*)d_in[3];
  const float* Wp = (const float*)d_in[4];
  const float* bp = (const float*)d_in[5];
  float* out = (float*)d_out;
  char* ws = (char*)d_ws;

  ushort* xb  = (ushort*)(ws);                      // [8192][1024] bf16
  ushort* wall = (ushort*)(ws + (16ull << 20));     // [3072][1024] = Wq^T|Wk^T|Wv^T
  ushort* wpT = (ushort*)(ws + (22ull << 20));      // [1024][1024]
  ushort* qb  = (ushort*)(ws + (24ull << 20));      // [64][2048][64] (pre-scaled)
  ushort* kb  = (ushort*)(ws + (40ull << 20));      // [64][2048][64]
  ushort* vTb = (ushort*)(ws + (56ull << 20));      // [64][64][2048]
  ushort* aob = (ushort*)(ws + (72ull << 20));      // [8192][1024]

  prep_kernel<<<dim3(32, 32, 12), dim3(32, 8), 0, stream>>>(x, Wq, Wk, Wv, Wp, xb, wall, wpT);

  // QKV: one merged GEMM, N = 3*16*64 = 3072 (wall rows = sel*1024 + h*64 + d)
  gemm_kernel<0><<<dim3(64 * 24), 256, 0, stream>>>(xb, wall, nullptr, nullptr, qb, kb, vTb);
  attn_kernel<<<dim3(1024), 256, 0, stream>>>(qb, kb, vTb, aob);
  gemm_kernel<1><<<dim3(64 * 8), 256, 0, stream>>>(aob, wpT, bp, out, nullptr, nullptr, nullptr);
}

// Round 17
// 173.472 us; speedup vs baseline: 1.0336x; 1.0336x over previous
//
#include <hip/hip_runtime.h>

#define TSEQ 2048
#define CDIM 1024
#define NH 16
#define DH 64
#define NB 4

typedef __bf16 bf16x8 __attribute__((ext_vector_type(8)));
typedef float f32x4 __attribute__((ext_vector_type(4)));

// 1/sqrt(C) * log2(e): folded into Q so softmax runs in exp2 domain
#define QSCALE 0.04508422f

static __device__ __forceinline__ ushort f2bf(float f) {
  unsigned u = __float_as_uint(f);
  unsigned r = u + 0x7fffu + ((u >> 16) & 1u);
  return (ushort)(r >> 16);
}

static __device__ __forceinline__ uint cvtpk(float lo, float hi) {
  uint r;
  asm("v_cvt_pk_bf16_f32 %0, %1, %2" : "=v"(r) : "v"(lo), "v"(hi));
  return r;
}

// global(16B, per-lane addr) -> LDS (wave-uniform base, HW adds lane*16)
static __device__ __forceinline__ void gload_lds16(const void* g, void* ldsbase) {
  __builtin_amdgcn_global_load_lds((const __attribute__((address_space(1))) void*)g,
                                   (__attribute__((address_space(3))) void*)ldsbase,
                                   16, 0, 0);
}

// ONE prep launch. z<3: W{q,k,v}[16][1024][64] -> wall [z][head][64][1024];
// z==3: Wp -> wpT; z in [4,12): x f32 -> xb bf16 (plane p covers 1024 blocks
// x 256 threads x float4 = 1M elems; 8 planes = 8.4M = NB*TSEQ*CDIM exactly).
__global__ void prep_kernel(const float* __restrict__ x,
                            const float* __restrict__ Wq, const float* __restrict__ Wk,
                            const float* __restrict__ Wv, const float* __restrict__ Wp,
                            ushort* __restrict__ xb, ushort* __restrict__ wall,
                            ushort* __restrict__ wpT) {
  __shared__ float tile[32][33];
  const int z = blockIdx.z;
  const int tx = threadIdx.x, ty = threadIdx.y;
  if (z >= 4) {
    int blk = (z - 4) * 1024 + blockIdx.y * 32 + blockIdx.x;
    int i = blk * 256 + ty * 32 + tx;
    float4 f = ((const float4*)x)[i];
    ushort4 o;
    o.x = f2bf(f.x); o.y = f2bf(f.y); o.z = f2bf(f.z); o.w = f2bf(f.w);
    ((ushort4*)xb)[i] = o;
    return;
  }
  const float* s; ushort* d; int Cc, c0, r0;
  if (z < 3) {
    const int head = blockIdx.x >> 1;
    s = (z == 0 ? Wq : z == 1 ? Wk : Wv) + (size_t)head * CDIM * DH;
    d = wall + ((size_t)z << 20) + (size_t)head * CDIM * DH;
    Cc = DH; c0 = (blockIdx.x & 1) * 32; r0 = blockIdx.y * 32;
  } else {
    s = Wp; d = wpT; Cc = CDIM; c0 = blockIdx.x * 32; r0 = blockIdx.y * 32;
  }
  for (int i = ty; i < 32; i += 8)
    tile[i][tx] = s[(size_t)(r0 + i) * Cc + c0 + tx];
  __syncthreads();
  for (int i = ty; i < 32; i += 8)
    d[(size_t)(c0 + i) * CDIM + r0 + tx] = f2bf(tile[tx][i]);
}

// 128x128-tile GEMM (R9/R13 structure, best measured): BK=32 double-buffer at
// 32KB LDS, one __syncthreads per step, stage(k+1) issued before compute(k).
// Rows are 64B; swizzle chunk ^= (row>>1)&3 is conflict-free on ds_read_b128.
// MODE 0: qkv (B^T = [3072][1024]; route by n). MODE 1: proj (f32 + bias).
// XCD chunk is nt-fastest: each XCD reads only 8 A-panels (2 MB, L2-resident).
template <int MODE>
__global__ __launch_bounds__(256) void gemm_kernel(
    const ushort* __restrict__ A, const ushort* __restrict__ Bt,
    const float* __restrict__ bp, float* __restrict__ fout,
    ushort* __restrict__ qb, ushort* __restrict__ kb, ushort* __restrict__ vTb) {
  __shared__ ushort lds[16384]; // 2 buf x (A 8KB + B 8KB) = 32KB
  const int tid = threadIdx.x, w = tid >> 6, l = tid & 63;
  const int nwg = gridDim.x;
  const int bid = blockIdx.x;
  const int wgid = (bid & 7) * (nwg >> 3) + (bid >> 3);
  const int NT = (MODE == 0) ? 24 : 8;
  const int nt = wgid % NT, mt = wgid / NT;
  const int wr = w >> 1, wc = w & 1;
  const int srw = l >> 2;
  const int sck = l & 3;
  const int scol = (sck ^ ((srw >> 1) & 3)) * 8;
  const int g = l >> 4;
  char* ldsb = (char*)lds;

  f32x4 acc[4][4] = {};

  const ushort* Arow = A + ((size_t)mt * 128) * CDIM;
  const ushort* Brow = Bt + ((size_t)nt * 128) * CDIM;

#pragma unroll
  for (int i = 0; i < 4; ++i) {
    int ch = w * 4 + i;
    const ushort* src = (ch < 8) ? Arow + (size_t)(ch * 16 + srw) * CDIM + scol
                                 : Brow + (size_t)((ch - 8) * 16 + srw) * CDIM + scol;
    gload_lds16(src, ldsb + ch * 1024);
  }

  for (int k0 = 0; k0 < CDIM; k0 += 32) {
    const int bsel = (k0 >> 5) & 1;
    char* base = ldsb + bsel * 16384;
    __syncthreads();
    if (k0 + 32 < CDIM) {
      char* nb = ldsb + (bsel ^ 1) * 16384;
#pragma unroll
      for (int i = 0; i < 4; ++i) {
        int ch = w * 4 + i;
        const ushort* src = (ch < 8)
            ? Arow + (size_t)(ch * 16 + srw) * CDIM + k0 + 32 + scol
            : Brow + (size_t)((ch - 8) * 16 + srw) * CDIM + k0 + 32 + scol;
        gload_lds16(src, nb + ch * 1024);
      }
    }
    bf16x8 af[4];
#pragma unroll
    for (int fm = 0; fm < 4; ++fm) {
      int row = wr * 64 + fm * 16 + (l & 15);
      af[fm] = *(const bf16x8*)(base + row * 64 + ((g ^ ((row >> 1) & 3)) << 4));
    }
#pragma unroll
    for (int fn = 0; fn < 4; ++fn) {
      int n = wc * 64 + fn * 16 + (l & 15);
      bf16x8 bfr = *(const bf16x8*)(base + 8192 + n * 64 + ((g ^ ((n >> 1) & 3)) << 4));
#pragma unroll
      for (int fm = 0; fm < 4; ++fm)
        acc[fm][fn] = __builtin_amdgcn_mfma_f32_16x16x32_bf16(af[fm], bfr, acc[fm][fn], 0, 0, 0);
    }
  }

#pragma unroll
  for (int fm = 0; fm < 4; ++fm) {
#pragma unroll
    for (int fn = 0; fn < 4; ++fn) {
      const int gr0 = mt * 128 + wr * 64 + fm * 16 + (l >> 4) * 4;
      const int gc = nt * 128 + wc * 64 + fn * 16 + (l & 15);
      if (MODE == 1) {
        float bias = bp[gc];
#pragma unroll
        for (int r = 0; r < 4; ++r)
          fout[(size_t)(gr0 + r) * CDIM + gc] = acc[fm][fn][r] + bias;
      } else {
        const int sel = gc >> 10, h = (gc >> 6) & 15, d = gc & 63;
        const int bh = (gr0 >> 11) * NH + h, tl = gr0 & 2047;
        if (sel == 2) {
          ushort4 pk;
          pk.x = f2bf(acc[fm][fn][0]); pk.y = f2bf(acc[fm][fn][1]);
          pk.z = f2bf(acc[fm][fn][2]); pk.w = f2bf(acc[fm][fn][3]);
          *(ushort4*)(vTb + ((size_t)bh * DH + d) * TSEQ + tl) = pk;
        } else if (sel == 0) {
#pragma unroll
          for (int r = 0; r < 4; ++r)
            qb[((size_t)bh * TSEQ + tl + r) * DH + d] = f2bf(acc[fm][fn][r] * QSCALE);
        } else {
#pragma unroll
          for (int r = 0; r < 4; ++r)
            kb[((size_t)bh * TSEQ + tl + r) * DH + d] = f2bf(acc[fm][fn][r]);
        }
      }
    }
  }
}

// Flash attention (R9/R13 structure, verified): 1024 blocks x 256 threads
// (4 waves), 128-q tile, qt-descending + XCD-aware decode, KVBLK=64
// double-buffered, swapped QK^T, no cross-lane ops in the softmax common path.
__global__ __launch_bounds__(256, 3) void attn_kernel(
    const ushort* __restrict__ qb, const ushort* __restrict__ kb,
    const ushort* __restrict__ vTb, ushort* __restrict__ aob) {
  __shared__ ushort lds[16384];
  char* ldsb = (char*)lds;
  const int tid = threadIdx.x, w = tid >> 6, l = tid & 63;
  const int id = blockIdx.x;
  const int bh = (id & 7) * 8 + ((id >> 3) & 7);
  const int qt = 15 - (id >> 6);
  const int q0 = qt * 128;
  const int nt = 2 * (qt + 1);
  const int b = bh >> 4, h = bh & 15;
  const int g = l >> 4, q = l & 15;
  const int srow = l >> 3;
  const int scol = (((l & 7) ^ srow) << 3);
  const int adrA = ((l & 16) << 1 | q) << 2;
  const int adrB = adrA + 64;
  const bool hi32 = (l & 32) != 0;

  bf16x8 qf[2][2];
#pragma unroll
  for (int qs = 0; qs < 2; ++qs) {
    const ushort* qrow = qb + ((size_t)bh * TSEQ + q0 + w * 32 + qs * 16 + q) * DH;
    qf[qs][0] = *(const bf16x8*)(qrow + 8 * g);
    qf[qs][1] = *(const bf16x8*)(qrow + 32 + 8 * g);
  }

  float m[2] = {0.f, 0.f}, lsum[2] = {0.f, 0.f};
  f32x4 o[4][2] = {};

#pragma unroll
  for (int i = 0; i < 4; ++i) {
    int ch = w * 4 + i;
    if (ch < 8)
      gload_lds16(kb + ((size_t)bh * TSEQ + ch * 8 + srow) * DH + scol, ldsb + ch * 1024);
    else {
      int d = (ch - 8) * 8 + srow;
      gload_lds16(vTb + ((size_t)bh * DH + d) * TSEQ + scol, ldsb + 16384 + (ch - 8) * 1024);
    }
  }

#pragma unroll 1
  for (int j = 0; j < nt; ++j) {
    __syncthreads();
    const int cbuf = j & 1;
    if (j + 1 < nt) {
      const int kvn = (j + 1) * 64, nb = (j + 1) & 1;
#pragma unroll
      for (int i = 0; i < 4; ++i) {
        int ch = w * 4 + i;
        if (ch < 8)
          gload_lds16(kb + ((size_t)bh * TSEQ + kvn + ch * 8 + srow) * DH + scol,
                      ldsb + nb * 8192 + ch * 1024);
        else {
          int d = (ch - 8) * 8 + srow;
          gload_lds16(vTb + ((size_t)bh * DH + d) * TSEQ + kvn + scol,
                      ldsb + 16384 + nb * 8192 + (ch - 8) * 1024);
        }
      }
    }
    char* Kb = ldsb + cbuf * 8192;
    char* Vb = ldsb + 16384 + cbuf * 8192;

    f32x4 s[4][2] = {};
    __builtin_amdgcn_s_setprio(1);
#pragma unroll
    for (int ks = 0; ks < 2; ++ks)
#pragma unroll
      for (int fn = 0; fn < 4; ++fn) {
        int n = fn * 16 + q;
        int cbb = (ks * 64 + 16 * g) ^ ((n & 7) << 4);
        bf16x8 kf = *(const bf16x8*)(Kb + n * 128 + cbb);
        s[fn][0] = __builtin_amdgcn_mfma_f32_16x16x32_bf16(kf, qf[0][ks], s[fn][0], 0, 0, 0);
        s[fn][1] = __builtin_amdgcn_mfma_f32_16x16x32_bf16(kf, qf[1][ks], s[fn][1], 0, 0, 0);
      }
    __builtin_amdgcn_s_setprio(0);

    if (j >= nt - 2) {
#pragma unroll
      for (int qs = 0; qs < 2; ++qs) {
        int rowloc = q0 + w * 32 + qs * 16 + q - j * 64;
#pragma unroll
        for (int fn = 0; fn < 4; ++fn)
#pragma unroll
          for (int r = 0; r < 4; ++r)
            if (fn * 16 + 4 * g + r > rowloc) s[fn][qs][r] = -1e30f;
      }
    }

    float vmx[2];
#pragma unroll
    for (int qs = 0; qs < 2; ++qs) {
      float v = fmaxf(fmaxf(fmaxf(s[0][qs][0], s[0][qs][1]), fmaxf(s[0][qs][2], s[0][qs][3])),
                      fmaxf(fmaxf(s[1][qs][0], s[1][qs][1]), fmaxf(s[1][qs][2], s[1][qs][3])));
      v = fmaxf(v, fmaxf(fmaxf(fmaxf(s[2][qs][0], s[2][qs][1]), fmaxf(s[2][qs][2], s[2][qs][3])),
                         fmaxf(fmaxf(s[3][qs][0], s[3][qs][1]), fmaxf(s[3][qs][2], s[3][qs][3]))));
      vmx[qs] = v;
    }
    if (__any(fmaxf(vmx[0] - m[0], vmx[1] - m[1]) > 8.f)) {
      float fc[2];
#pragma unroll
      for (int qs = 0; qs < 2; ++qs) {
        float v = vmx[qs];
        v = fmaxf(v, __shfl_xor(v, 16));
        v = fmaxf(v, __shfl_xor(v, 32));
        float mn = fmaxf(m[qs], v);
        fc[qs] = __builtin_amdgcn_exp2f(m[qs] - mn);
        m[qs] = mn; lsum[qs] *= fc[qs];
      }
#pragma unroll
      for (int r = 0; r < 4; ++r) {
        float f0 = __shfl(fc[0], (l & 0x30) | (4 * g + r), 64);
        float f1 = __shfl(fc[1], (l & 0x30) | (4 * g + r), 64);
#pragma unroll
        for (int fn = 0; fn < 4; ++fn) { o[fn][0][r] *= f0; o[fn][1][r] *= f1; }
      }
    }

    uint D[2][4][2];
#pragma unroll
    for (int qs = 0; qs < 2; ++qs) {
      float rs = 0.f;
#pragma unroll
      for (int fn = 0; fn < 4; ++fn) {
        float p0 = __builtin_amdgcn_exp2f(s[fn][qs][0] - m[qs]);
        float p1 = __builtin_amdgcn_exp2f(s[fn][qs][1] - m[qs]);
        float p2 = __builtin_amdgcn_exp2f(s[fn][qs][2] - m[qs]);
        float p3 = __builtin_amdgcn_exp2f(s[fn][qs][3] - m[qs]);
        rs += (p0 + p1) + (p2 + p3);
        D[qs][fn][0] = cvtpk(p0, p1);
        D[qs][fn][1] = cvtpk(p2, p3);
      }
      lsum[qs] += rs;
    }

#pragma unroll
    for (int ksg = 0; ksg < 2; ++ksg) {
      union { uint u[4]; bf16x8 v; } P[2];
#pragma unroll
      for (int qs = 0; qs < 2; ++qs) {
        uint t0a = __builtin_amdgcn_ds_bpermute(adrA, (int)D[qs][2 * ksg][0]);
        uint t0b = __builtin_amdgcn_ds_bpermute(adrA, (int)D[qs][2 * ksg + 1][0]);
        uint t1a = __builtin_amdgcn_ds_bpermute(adrA, (int)D[qs][2 * ksg][1]);
        uint t1b = __builtin_amdgcn_ds_bpermute(adrA, (int)D[qs][2 * ksg + 1][1]);
        uint t2a = __builtin_amdgcn_ds_bpermute(adrB, (int)D[qs][2 * ksg][0]);
        uint t2b = __builtin_amdgcn_ds_bpermute(adrB, (int)D[qs][2 * ksg + 1][0]);
        uint t3a = __builtin_amdgcn_ds_bpermute(adrB, (int)D[qs][2 * ksg][1]);
        uint t3b = __builtin_amdgcn_ds_bpermute(adrB, (int)D[qs][2 * ksg + 1][1]);
        P[qs].u[0] = hi32 ? t0b : t0a;
        P[qs].u[1] = hi32 ? t1b : t1a;
        P[qs].u[2] = hi32 ? t2b : t2a;
        P[qs].u[3] = hi32 ? t3b : t3a;
      }
      __builtin_amdgcn_s_setprio(1);
#pragma unroll
      for (int fn = 0; fn < 4; ++fn) {
        int n = fn * 16 + q;
        int cbb = (ksg * 64 + 16 * g) ^ ((n & 7) << 4);
        bf16x8 vf = *(const bf16x8*)(Vb + n * 128 + cbb);
        o[fn][0] = __builtin_amdgcn_mfma_f32_16x16x32_bf16(P[0].v, vf, o[fn][0], 0, 0, 0);
        o[fn][1] = __builtin_amdgcn_mfma_f32_16x16x32_bf16(P[1].v, vf, o[fn][1], 0, 0, 0);
      }
      __builtin_amdgcn_s_setprio(0);
    }
  }

#pragma unroll
  for (int qs = 0; qs < 2; ++qs) {
    float tot = lsum[qs];
    tot += __shfl_xor(tot, 16);
    tot += __shfl_xor(tot, 32);
    float inv = 1.f / tot;
#pragma unroll
    for (int r = 0; r < 4; ++r) {
      float invq = __shfl(inv, (l & 0x30) | (4 * g + r), 64);
      int t = q0 + w * 32 + qs * 16 + 4 * g + r;
#pragma unroll
      for (int fn = 0; fn < 4; ++fn) {
        int d = fn * 16 + q;
        aob[((size_t)b * TSEQ + t) * (NH * DH) + h * DH + d] = f2bf(o[fn][qs][r] * invq);
      }
    }
  }
}

extern "C" void kernel_launch(void* const* d_in, const int* in_sizes, int n_in,
                              void* d_out, int out_size, void* d_ws, size_t ws_size,
                              hipStream_t stream) {
  (void)in_sizes; (void)n_in; (void)out_size; (void)ws_size;
  const float* x  = (const float*)d_in[0];
  const float* Wq = (const float*)d_in[1];
  const float* Wk = (const float*)d_in[2];
  const float* Wv = (const float*)d_in[3];
  const float* Wp = (const float*)d_in[4];
  const float* bp = (const float*)d_in[5];
  float* out = (float*)d_out;
  char* ws = (char*)d_ws;

  ushort* xb  = (ushort*)(ws);                      // [8192][1024] bf16
  ushort* wall = (ushort*)(ws + (16ull << 20));     // [3072][1024] = Wq^T|Wk^T|Wv^T
  ushort* wpT = (ushort*)(ws + (22ull << 20));      // [1024][1024]
  ushort* qb  = (ushort*)(ws + (24ull << 20));      // [64][2048][64] (pre-scaled)
  ushort* kb  = (ushort*)(ws + (40ull << 20));      // [64][2048][64]
  ushort* vTb = (ushort*)(ws + (56ull << 20));      // [64][64][2048]
  ushort* aob = (ushort*)(ws + (72ull << 20));      // [8192][1024]

  prep_kernel<<<dim3(32, 32, 12), dim3(32, 8), 0, stream>>>(x, Wq, Wk, Wv, Wp, xb, wall, wpT);

  // QKV: one merged GEMM, N = 3*16*64 = 3072 (wall rows = sel*1024 + h*64 + d)
  gemm_kernel<0><<<dim3(64 * 24), 256, 0, stream>>>(xb, wall, nullptr, nullptr, qb, kb, vTb);
  attn_kernel<<<dim3(1024), 256, 0, stream>>>(qb, kb, vTb, aob);
  gemm_kernel<1><<<dim3(64 * 8), 256, 0, stream>>>(aob, wpT, bp, out, nullptr, nullptr, nullptr);
}